// Round 2
// baseline (482.835 us; speedup 1.0000x reference)
//
#include <hip/hip_runtime.h>
#include <hip/hip_bf16.h>
#include <stdint.h>

// SelfAttention: out = softmax((x Wq^T)(x Wk^T)^T / sqrt(D)) (x Wv^T)
// SEQ=8192, D=1024, fp32 in/out. All GEMMs bf16 MFMA.
// R11: faithful m201-style 8-phase K-loop (the verified 1563/1728 TF 256²
// template), replacing R10's coarse 4-phase split (which was neutral, per
// m196's "coarse split without fine interleave hurts").
//   Per K-tile t (buf c = t&1), 4 phases; each phase:
//     { ds_read fragment subtile ; stage ONE half-tile (2 gload_lds) ;
//       s_barrier ; lgkmcnt(0) ; setprio(1) ; 16 MFMA (one C-quadrant) ;
//       setprio(0) ; s_barrier }
//   Quadrants: Ph1 Q00 (reads A[mi0-3]x2k + B[ni0-1]x2k = 12),
//              Ph2 Q01 (reads B[ni2-3]x2k = 4, reuses A),
//              Ph3 Q10 (reads A[mi4-7]x2k = 8, reuses B),
//              Ph4 Q11 (0 reads).
//   Stages: Ph1-3 -> tile t+1 {Ah1,Bh0,Bh1} into buf c^1 (its old reads
//   retired at t-1's Ph3 barrier); Ph4 -> tile t+2 Ah0 into buf c.
//   vmcnt(2) once per K-tile at Ph4 (1 half-tile in flight, never drain-0):
//   outstanding there = tile t+1 (8 loads) + t+2.Ah0 (2) -> waits t+1 landed
//   before next K-tile's reads. All hazards barrier-ordered (see comments).
// Keeps: row-rotation LDS swizzle (0 bank conflicts), GROUP_M=8 L2 grouping,
// compact q/k/v de-interleave, fused softmax epilogues (MODE1 exp2 + atomic
// row sums, MODE2 1/l), split-K=2 PV (grid=256 = 1 block/CU).
//
// Workspace (~230 MB): x_bf16 16 | Wcat 6 | q 16 | k 16 | v 16 | S 128 | pv 32
//                      | lsum 32KB

#define SEQ 8192
#define DMODEL 1024
#define LOG2E 1.44269504088896340736f
#define GROUP_M 8

typedef __bf16 bf16_t;
typedef __bf16 bf16x8 __attribute__((ext_vector_type(8)));
typedef float f32x4 __attribute__((ext_vector_type(4)));

// ---------------- fp32 -> bf16 convert ----------------
__global__ __launch_bounds__(256)
void convert_f32_bf16(const float* __restrict__ in, bf16_t* __restrict__ out, long n) {
    long i = ((long)blockIdx.x * 256 + threadIdx.x) * 4;
    if (i + 3 < n) {
        const float4 v = *(const float4*)(in + i);
        union { ushort4 u; bf16_t b[4]; } p;
        p.b[0] = (bf16_t)v.x; p.b[1] = (bf16_t)v.y;
        p.b[2] = (bf16_t)v.z; p.b[3] = (bf16_t)v.w;
        *(ushort4*)(out + i) = p.u;
    }
}

// ---------------- fp32 add: out += part ----------------
__global__ __launch_bounds__(256)
void add_f32(float* __restrict__ out, const float* __restrict__ part, long n) {
    long i = ((long)blockIdx.x * 256 + threadIdx.x) * 4;
    if (i + 3 < n) {
        float4 a = *(const float4*)(out + i);
        const float4 b = *(const float4*)(part + i);
        a.x += b.x; a.y += b.y; a.z += b.z; a.w += b.w;
        *(float4*)(out + i) = a;
    }
}

// ---------------- zero fp32 buffer ----------------
__global__ __launch_bounds__(256)
void zero_f32(float* __restrict__ p, int n) {
    int i = blockIdx.x * 256 + threadIdx.x;
    if (i < n) p[i] = 0.0f;
}

// ---------------- NT GEMM: C[M,N] = A[M,K] @ B[N,K]^T ----------------
// 256x256 tile, BK=64, 512 threads (8 waves as 2x4), per-wave 128x64 via
// 8x4 grid of mfma_f32_16x16x32_bf16. 8-phase deep pipeline (see header).
// MODE 0: C = alpha*acc. MODE 1: C = exp2(alpha*acc) bf16 + atomic row sums.
// MODE 2: C = acc / lsum[row].
template <typename OutT, int MODE>
__global__ __launch_bounds__(512, 2)
void gemm_nt(const bf16_t* __restrict__ A, const bf16_t* __restrict__ B,
             OutT* __restrict__ C0, OutT* __restrict__ C1,
             float* __restrict__ lsum,
             int M, int N, int Kps, int lda, int ldb, int ldc,
             long plane, int cshift, float alpha)
{
    __shared__ bf16_t As[2][256 * 64];
    __shared__ bf16_t Bs[2][256 * 64];

    const int tid  = threadIdx.x;
    const int wave = tid >> 6;
    const int lane = tid & 63;

    const int nbm = M >> 8, nbn = N >> 8;
    const int tiles = nbm * nbn;
    int bid = blockIdx.x;
    const int sid = bid / tiles;        // split-K id
    bid -= sid * tiles;
    const long kbase = (long)sid * Kps;
    OutT* __restrict__ C = sid ? C1 : C0;

    // grouped swizzle for L2 locality
    const int per_group = GROUP_M * nbn;
    const int gid   = bid / per_group;
    const int rem   = bid - gid * per_group;
    const int first = gid * GROUP_M;
    const int gsz   = min(nbm - first, GROUP_M);
    const int bm    = first + rem % gsz;
    const int bn    = rem / gsz;
    const long row0 = (long)bm * 256;
    const long col0 = (long)bn * 256;

    const int wm = (wave >> 2) * 128;  // wave's 128x64 sub-tile
    const int wn = (wave & 3) * 64;
    const int lr = lane & 15;          // fragment non-K index
    const int lq = lane >> 4;          // quad 0..3 -> k-chunk / row group

    // --- staging addresses: rows rt=tid>>3 per 64-row block i; phys slot
    // p=tid&7 holds global chunk (p+r)&7 (rotation within the 128B row).
    const int rt = tid >> 3;
    const int sl = ((tid & 7) + rt) & 7;
    const bf16_t* pa = A + (row0 + rt) * (long)lda + kbase + sl * 8;
    const bf16_t* pb = B + (col0 + rt) * (long)ldb + kbase + sl * 8;

    // --- LDS read offsets. For row r, wanted chunk g: p = (g - r)&7;
    // r&7 == lr&7 for all mi/ni, so p depends only on (lq,lr,ks).
    const int p0  = (lq - lr) & 7;          // ks=0 chunk = lq
    const int p1  = p0 ^ 4;                 // ks=1 chunk = 4+lq
    const int oA0 = (wm + lr) * 64 + p0 * 8;
    const int oA1 = (wm + lr) * 64 + p1 * 8;
    const int oB0 = (wn + lr) * 64 + p0 * 8;
    const int oB1 = (wn + lr) * 64 + p1 * 8;

    const int nt = Kps >> 6;

    f32x4 acc[8][4] = {};

    // One half-tile = 2 row-blocks of 64 rows = 2 gload_lds per thread.
    // A half0 = row blocks 0,1 ; half1 = 2,3 (same for B).
#define STG_A(kt, bsel, i0)                                                     \
    {                                                                           \
        _Pragma("unroll")                                                       \
        for (int ii = 0; ii < 2; ++ii) {                                        \
            const int i = (i0) + ii;                                            \
            const bf16_t* ga = pa + (long)(kt) * 64 + (long)i * 64 * lda;       \
            __builtin_amdgcn_global_load_lds(                                   \
                (const __attribute__((address_space(1))) uint32_t*)ga,          \
                (__attribute__((address_space(3))) uint32_t*)(As[bsel] + i * 4096 + tid * 8), \
                16, 0, 0);                                                      \
        }                                                                       \
    }
#define STG_B(kt, bsel, i0)                                                     \
    {                                                                           \
        _Pragma("unroll")                                                       \
        for (int ii = 0; ii < 2; ++ii) {                                        \
            const int i = (i0) + ii;                                            \
            const bf16_t* gb = pb + (long)(kt) * 64 + (long)i * 64 * ldb;       \
            __builtin_amdgcn_global_load_lds(                                   \
                (const __attribute__((address_space(1))) uint32_t*)gb,          \
                (__attribute__((address_space(3))) uint32_t*)(Bs[bsel] + i * 4096 + tid * 8), \
                16, 0, 0);                                                      \
        }                                                                       \
    }

    // Prologue: tile 0 fully (4 halves) + tile 1 Ah0, then wait tile 0.
    STG_A(0, 0, 0); STG_A(0, 0, 2); STG_B(0, 0, 0); STG_B(0, 0, 2);
    if (nt > 1) STG_A(1, 1, 0);
    asm volatile("s_waitcnt vmcnt(2)" ::: "memory");
    __builtin_amdgcn_s_barrier();

    for (int t = 0; t < nt; ++t) {
        const int c = t & 1;
        const bf16_t* as = As[c];
        const bf16_t* bs = Bs[c];
        const int s1 = (t + 1 < nt);    // stage tile t+1 (into buf c^1)
        const int s2 = (t + 2 < nt);    // stage tile t+2 Ah0 (into buf c)

        bf16x8 a0k0[4], a0k1[4], a1k0[4], a1k1[4];
        bf16x8 b0k0[2], b0k1[2], b1k0[2], b1k1[2];

        // ================= Ph1: Q00 (mi0-3 x ni0-1) =================
        // 12 ds_reads; stage (t+1).Ah1. Buf c tile t landed: vmcnt(2)+barrier
        // at t-1's Ph4. Buf c^1 old reads retired at t-1's Ph3 barrier.
        #pragma unroll
        for (int mi = 0; mi < 4; ++mi) {
            a0k0[mi] = *(const bf16x8*)(as + oA0 + mi * 1024);
            a0k1[mi] = *(const bf16x8*)(as + oA1 + mi * 1024);
        }
        #pragma unroll
        for (int ni = 0; ni < 2; ++ni) {
            b0k0[ni] = *(const bf16x8*)(bs + oB0 + ni * 1024);
            b0k1[ni] = *(const bf16x8*)(bs + oB1 + ni * 1024);
        }
        if (s1) STG_A(t + 1, c ^ 1, 2);
        asm volatile("s_waitcnt lgkmcnt(8)" ::: "memory");  // pace the 12-read phase
        __builtin_amdgcn_s_barrier();
        asm volatile("s_waitcnt lgkmcnt(0)" ::: "memory");
        __builtin_amdgcn_s_setprio(1);
        #pragma unroll
        for (int mi = 0; mi < 4; ++mi)
            #pragma unroll
            for (int ni = 0; ni < 2; ++ni)
                acc[mi][ni] = __builtin_amdgcn_mfma_f32_16x16x32_bf16(
                    a0k0[mi], b0k0[ni], acc[mi][ni], 0, 0, 0);
        #pragma unroll
        for (int mi = 0; mi < 4; ++mi)
            #pragma unroll
            for (int ni = 0; ni < 2; ++ni)
                acc[mi][ni] = __builtin_amdgcn_mfma_f32_16x16x32_bf16(
                    a0k1[mi], b0k1[ni], acc[mi][ni], 0, 0, 0);
        __builtin_amdgcn_s_setprio(0);
        __builtin_amdgcn_s_barrier();

        // ================= Ph2: Q01 (mi0-3 x ni2-3) =================
        #pragma unroll
        for (int ni = 0; ni < 2; ++ni) {
            b1k0[ni] = *(const bf16x8*)(bs + oB0 + (ni + 2) * 1024);
            b1k1[ni] = *(const bf16x8*)(bs + oB1 + (ni + 2) * 1024);
        }
        if (s1) STG_B(t + 1, c ^ 1, 0);
        __builtin_amdgcn_s_barrier();
        asm volatile("s_waitcnt lgkmcnt(0)" ::: "memory");
        __builtin_amdgcn_s_setprio(1);
        #pragma unroll
        for (int mi = 0; mi < 4; ++mi)
            #pragma unroll
            for (int ni = 0; ni < 2; ++ni)
                acc[mi][ni + 2] = __builtin_amdgcn_mfma_f32_16x16x32_bf16(
                    a0k0[mi], b1k0[ni], acc[mi][ni + 2], 0, 0, 0);
        #pragma unroll
        for (int mi = 0; mi < 4; ++mi)
            #pragma unroll
            for (int ni = 0; ni < 2; ++ni)
                acc[mi][ni + 2] = __builtin_amdgcn_mfma_f32_16x16x32_bf16(
                    a0k1[mi], b1k1[ni], acc[mi][ni + 2], 0, 0, 0);
        __builtin_amdgcn_s_setprio(0);
        __builtin_amdgcn_s_barrier();

        // ================= Ph3: Q10 (mi4-7 x ni0-1) =================
        #pragma unroll
        for (int mi = 0; mi < 4; ++mi) {
            a1k0[mi] = *(const bf16x8*)(as + oA0 + (mi + 4) * 1024);
            a1k1[mi] = *(const bf16x8*)(as + oA1 + (mi + 4) * 1024);
        }
        if (s1) STG_B(t + 1, c ^ 1, 2);
        __builtin_amdgcn_s_barrier();
        asm volatile("s_waitcnt lgkmcnt(0)" ::: "memory");
        __builtin_amdgcn_s_setprio(1);
        #pragma unroll
        for (int mi = 0; mi < 4; ++mi)
            #pragma unroll
            for (int ni = 0; ni < 2; ++ni)
                acc[mi + 4][ni] = __builtin_amdgcn_mfma_f32_16x16x32_bf16(
                    a1k0[mi], b0k0[ni], acc[mi + 4][ni], 0, 0, 0);
        #pragma unroll
        for (int mi = 0; mi < 4; ++mi)
            #pragma unroll
            for (int ni = 0; ni < 2; ++ni)
                acc[mi + 4][ni] = __builtin_amdgcn_mfma_f32_16x16x32_bf16(
                    a1k1[mi], b0k1[ni], acc[mi + 4][ni], 0, 0, 0);
        __builtin_amdgcn_s_setprio(0);
        __builtin_amdgcn_s_barrier();
        // All buf-c LDS reads for tile t retired here (lgkm0 + barrier above).

        // ================= Ph4: Q11 (mi4-7 x ni2-3), 0 ds_reads ======
        // Stage (t+2).Ah0 into buf c (safe: reads done). vmcnt(2):
        // outstanding = tile t+1 (8) + (t+2).Ah0 (2) -> tile t+1 landed
        // before next iteration's Ph1 reads; counted, never drain-0.
        if (s2) STG_A(t + 2, c, 0);
        asm volatile("s_waitcnt vmcnt(2)" ::: "memory");
        __builtin_amdgcn_s_barrier();
        __builtin_amdgcn_s_setprio(1);
        #pragma unroll
        for (int mi = 0; mi < 4; ++mi)
            #pragma unroll
            for (int ni = 0; ni < 2; ++ni)
                acc[mi + 4][ni + 2] = __builtin_amdgcn_mfma_f32_16x16x32_bf16(
                    a1k0[mi], b1k0[ni], acc[mi + 4][ni + 2], 0, 0, 0);
        #pragma unroll
        for (int mi = 0; mi < 4; ++mi)
            #pragma unroll
            for (int ni = 0; ni < 2; ++ni)
                acc[mi + 4][ni + 2] = __builtin_amdgcn_mfma_f32_16x16x32_bf16(
                    a1k1[mi], b1k1[ni], acc[mi + 4][ni + 2], 0, 0, 0);
        __builtin_amdgcn_s_setprio(0);
        __builtin_amdgcn_s_barrier();
    }
#undef STG_A
#undef STG_B

    // Epilogue: C/D layout col=lane&15, row=(lane>>4)*4+reg  [m89/m91 verified]
    OutT* __restrict__ Cb = C + (col0 >> cshift) * plane;
    const int ccol0 = (int)(col0 & (((long)1 << cshift) - 1));

    if (MODE == 1) {
        // P' = exp2(alpha*acc); row partial sums -> shfl over lr -> atomicAdd.
        #pragma unroll
        for (int mi = 0; mi < 8; ++mi)
            #pragma unroll
            for (int rg = 0; rg < 4; ++rg) {
                const long r = row0 + wm + mi * 16 + lq * 4 + rg;
                float part = 0.f;
                #pragma unroll
                for (int ni = 0; ni < 4; ++ni) {
                    const int c = ccol0 + wn + ni * 16 + lr;
                    const float e = exp2f(alpha * acc[mi][ni][rg]);
                    part += e;
                    Cb[r * (long)ldc + c] = (OutT)e;
                }
                part += __shfl_xor(part, 1);
                part += __shfl_xor(part, 2);
                part += __shfl_xor(part, 4);
                part += __shfl_xor(part, 8);
                if (lr == 0) atomicAdd(&lsum[r], part);
            }
    } else if (MODE == 2) {
        #pragma unroll
        for (int mi = 0; mi < 8; ++mi)
            #pragma unroll
            for (int rg = 0; rg < 4; ++rg) {
                const long r = row0 + wm + mi * 16 + lq * 4 + rg;
                const float inv = 1.0f / lsum[r];
                #pragma unroll
                for (int ni = 0; ni < 4; ++ni) {
                    const int c = ccol0 + wn + ni * 16 + lr;
                    Cb[r * (long)ldc + c] = (OutT)(acc[mi][ni][rg] * inv);
                }
            }
    } else {
        #pragma unroll
        for (int mi = 0; mi < 8; ++mi)
            #pragma unroll
            for (int ni = 0; ni < 4; ++ni)
                #pragma unroll
                for (int rg = 0; rg < 4; ++rg) {
                    const long r = row0 + wm + mi * 16 + lq * 4 + rg;
                    const int  c = ccol0 + wn + ni * 16 + lr;
                    Cb[r * (long)ldc + c] = (OutT)(alpha * acc[mi][ni][rg]);
                }
    }
}

// ---------------- bf16 transpose (strided in), v -> v^T ----------------
__global__ __launch_bounds__(256)
void transpose_bf16(const bf16_t* __restrict__ in, bf16_t* __restrict__ out,
                    int R, int ldin, int ldout)
{
    __shared__ bf16_t tile[32][33];
    const int tx = threadIdx.x & 31;
    const int ty = threadIdx.x >> 5;   // 0..7
    const int c0 = blockIdx.x * 32;
    const int r0 = blockIdx.y * 32;
    #pragma unroll
    for (int j = 0; j < 32; j += 8)
        tile[ty + j][tx] = in[(long)(r0 + ty + j) * ldin + c0 + tx];
    __syncthreads();
    #pragma unroll
    for (int j = 0; j < 32; j += 8)
        out[(long)(c0 + ty + j) * ldout + r0 + tx] = tile[tx][ty + j];
}

extern "C" void kernel_launch(void* const* d_in, const int* in_sizes, int n_in,
                              void* d_out, int out_size, void* d_ws, size_t ws_size,
                              hipStream_t stream)
{
    const float* x  = (const float*)d_in[0];
    const float* Wq = (const float*)d_in[1];
    const float* Wk = (const float*)d_in[2];
    const float* Wv = (const float*)d_in[3];
    float* out = (float*)d_out;

    char* ws = (char*)d_ws;
    const long XN = (long)SEQ * DMODEL;     // 8,388,608
    const long WN = (long)DMODEL * DMODEL;  // 1,048,576
    const long SN = (long)SEQ * SEQ;        // 67,108,864

    bf16_t* xb   = (bf16_t*)ws;                              // 16MB
    bf16_t* wcat = (bf16_t*)(ws + XN * 2);                   // 6MB [3072,1024]
    bf16_t* qb   = (bf16_t*)(ws + XN * 2 + WN * 6);          // 16MB compact
    bf16_t* kb   = qb + XN;                                  // 16MB compact
    bf16_t* vb   = qb + 2 * XN;                              // 16MB compact
    bf16_t* Sb   = (bf16_t*)(ws + XN * 2 + WN * 6 + XN * 6); // 128MB
    float*  pvp  = (float*)(ws + XN * 2 + WN * 6 + XN * 6 + SN * 2); // 32MB
    float*  lsum = (float*)(ws + XN * 2 + WN * 6 + XN * 6 + SN * 2 + XN * 4); // 32KB
    bf16_t* vtb  = xb;  // v^T overlays x_bf16 (x dead after QKV GEMM)

    const size_t base_need = (size_t)(XN * 2 + WN * 6 + XN * 6 + SN * 2);
    const bool use_split = ws_size >= base_need + XN * 4 + SEQ * 4;
    if (!use_split) lsum = (float*)(ws + base_need);  // reuse pvp slot

    convert_f32_bf16<<<(int)(XN / 4 / 256), 256, 0, stream>>>(x,  xb, XN);
    convert_f32_bf16<<<(int)(WN / 4 / 256), 256, 0, stream>>>(Wq, wcat,          WN);
    convert_f32_bf16<<<(int)(WN / 4 / 256), 256, 0, stream>>>(Wk, wcat + WN,     WN);
    convert_f32_bf16<<<(int)(WN / 4 / 256), 256, 0, stream>>>(Wv, wcat + 2 * WN, WN);
    zero_f32<<<SEQ / 256, 256, 0, stream>>>(lsum, SEQ);

    dim3 blk256(256);
    dim3 blk512(512);
    // qkv = x @ Wcat^T, de-interleaved into compact q|k|v (plane=XN, cshift=10)
    gemm_nt<bf16_t, 0><<<(SEQ / 256) * (3 * DMODEL / 256), blk512, 0, stream>>>(
        xb, wcat, qb, qb, nullptr, SEQ, 3 * DMODEL, DMODEL,
        DMODEL, DMODEL, DMODEL, XN, 10, 1.0f);

    // v^T for the PV GEMM (writes over dead x_bf16)
    transpose_bf16<<<dim3(DMODEL / 32, SEQ / 32), blk256, 0, stream>>>(
        vb, vtb, SEQ, DMODEL, SEQ);

    // P' = exp2((q@k^T) * scale * log2e), bf16; row sums -> lsum (atomic)
    gemm_nt<bf16_t, 1><<<(SEQ / 256) * (SEQ / 256), blk512, 0, stream>>>(
        qb, kb, Sb, Sb, lsum, SEQ, SEQ, DMODEL,
        DMODEL, DMODEL, SEQ, 0, 30, 0.03125f * LOG2E);

    // out = (P' @ v) / l  (PV epilogue applies 1/lsum[row]). Split-K=2 if ws.
    if (use_split) {
        gemm_nt<float, 2><<<2 * (SEQ / 256) * (DMODEL / 256), blk512, 0, stream>>>(
            Sb, vtb, out, pvp, lsum, SEQ, DMODEL, SEQ / 2,
            SEQ, SEQ, DMODEL, 0, 30, 1.0f);
        add_f32<<<(int)(XN / 4 / 256), 256, 0, stream>>>(out, pvp, XN);
    } else {
        gemm_nt<float, 2><<<(SEQ / 256) * (DMODEL / 256), blk512, 0, stream>>>(
            Sb, vtb, out, out, lsum, SEQ, DMODEL, SEQ,
            SEQ, SEQ, DMODEL, 0, 30, 1.0f);
    }
}